// Round 7
// baseline (737.943 us; speedup 1.0000x reference)
//
#include <hip/hip_runtime.h>
#include <hip/hip_bf16.h>
#include <cstdint>
#include <cstddef>

#define B_N 4096
#define S_N 64
#define H_N 768
#define L_N 5
#define TEMP_INV (1.0f / 0.07f)
#define BN_EPS 1e-5f

typedef __attribute__((ext_vector_type(8))) short short8;
typedef __attribute__((ext_vector_type(4))) float f32x4;

// ---------- async global->LDS 16B ----------
__device__ __forceinline__ void async_copy16(void* lds, const void* g) {
  __builtin_amdgcn_global_load_lds(
      (const __attribute__((address_space(1))) unsigned int*)g,
      (__attribute__((address_space(3))) unsigned int*)lds, 16, 0, 0);
}

__device__ __forceinline__ unsigned short bf16b(float x) {
  __hip_bfloat16 h = __float2bfloat16(x);
  return *reinterpret_cast<unsigned short*>(&h);
}
__device__ __forceinline__ void store_bf16x4(void* p, float4 v) {
  ushort4 o = make_ushort4(bf16b(v.x), bf16b(v.y), bf16b(v.z), bf16b(v.w));
  *reinterpret_cast<ushort4*>(p) = o;
}

// ---------- block reduction (256 threads = 4 waves) ----------
__device__ inline float block_reduce_sum256(float v, float* sbuf) {
#pragma unroll
  for (int off = 32; off > 0; off >>= 1) v += __shfl_down(v, off, 64);
  int lane = threadIdx.x & 63;
  int wid = threadIdx.x >> 6;
  __syncthreads();
  if (lane == 0) sbuf[wid] = v;
  __syncthreads();
  float r = 0.f;
  if (threadIdx.x == 0) r = sbuf[0] + sbuf[1] + sbuf[2] + sbuf[3];
  return r;  // valid on thread 0 only
}

// ---------- K1: fused extract + row norms + column stats (single seq pass) ----------
__global__ __launch_bounds__(256) void extract_kernel(
    const float* __restrict__ seq, __hip_bfloat16* __restrict__ zb,
    __hip_bfloat16* __restrict__ tb, float* __restrict__ zn_inv,
    float* __restrict__ thn_inv, float* __restrict__ sum_z,
    float* __restrict__ ssq_z, float* __restrict__ sum_t,
    float* __restrict__ ssq_t) {
  __shared__ float pr[8][6][3];  // row, {z,l0..l4}, wave
  int t = threadIdx.x;
  int wv = t >> 6, ln = t & 63;
  bool act = t < 192;
  int c4 = t * 4;
  int b0 = blockIdx.x * 8;
  float zs[4] = {}, zq[4] = {}, ts4[4] = {}, tq4[4] = {};
  for (int r = 0; r < 8; ++r) {
    int b = b0 + r;
    const float* base = seq + (size_t)b * (S_N * H_N);
    float pv[6] = {0.f, 0.f, 0.f, 0.f, 0.f, 0.f};
    if (act) {
      float4 z4 = *(const float4*)(base + c4);
      store_bf16x4(zb + (size_t)b * H_N + c4, z4);
      pv[0] = z4.x * z4.x + z4.y * z4.y + z4.z * z4.z + z4.w * z4.w;
      zs[0] += z4.x; zs[1] += z4.y; zs[2] += z4.z; zs[3] += z4.w;
      zq[0] += z4.x * z4.x; zq[1] += z4.y * z4.y;
      zq[2] += z4.z * z4.z; zq[3] += z4.w * z4.w;
#pragma unroll
      for (int l = 0; l < L_N; ++l) {
        float4 v4;
        if (l == 0) {
          float4 a4 = *(const float4*)(base + H_N + c4);
          float4 b4 = *(const float4*)(base + 2 * H_N + c4);
          v4 = make_float4(0.5f * (a4.x + b4.x), 0.5f * (a4.y + b4.y),
                           0.5f * (a4.z + b4.z), 0.5f * (a4.w + b4.w));
        } else {
          v4 = *(const float4*)(base + (size_t)(l + 2) * H_N + c4);
        }
        store_bf16x4(tb + ((size_t)b * L_N + l) * H_N + c4, v4);
        pv[1 + l] = v4.x * v4.x + v4.y * v4.y + v4.z * v4.z + v4.w * v4.w;
        ts4[0] += v4.x; ts4[1] += v4.y; ts4[2] += v4.z; ts4[3] += v4.w;
        tq4[0] += v4.x * v4.x; tq4[1] += v4.y * v4.y;
        tq4[2] += v4.z * v4.z; tq4[3] += v4.w * v4.w;
      }
    }
#pragma unroll
    for (int v = 0; v < 6; ++v) {
      float x = pv[v];
#pragma unroll
      for (int off = 32; off > 0; off >>= 1) x += __shfl_down(x, off, 64);
      if (ln == 0 && wv < 3) pr[r][v][wv] = x;
    }
  }
  __syncthreads();
  if (t < 48) {
    int r = t / 6, v = t - r * 6;
    float s = pr[r][v][0] + pr[r][v][1] + pr[r][v][2];
    float inv = 1.f / fmaxf(sqrtf(s), 1e-12f);
    int b = b0 + r;
    if (v == 0) zn_inv[b] = inv;
    else thn_inv[b * L_N + (v - 1)] = inv;
  }
  if (act) {
#pragma unroll
    for (int j = 0; j < 4; ++j) {
      atomicAdd(&sum_z[c4 + j], zs[j]);
      atomicAdd(&ssq_z[c4 + j], zq[j]);
      atomicAdd(&sum_t[c4 + j], ts4[j]);
      atomicAdd(&ssq_t[c4 + j], tq4[j]);
    }
  }
}

// ---------- label histogram ----------
__global__ void count_kernel(const int* __restrict__ labels, int* __restrict__ cnt) {
  int i = blockIdx.x * 256 + threadIdx.x;
  if (i < B_N) atomicAdd(&cnt[labels[i]], 1);
}

// ---------- K3: bn affine coefficients ----------
__global__ void finalize_kernel(
    const float* __restrict__ sum_z, const float* __restrict__ ssq_z,
    const float* __restrict__ sum_t, const float* __restrict__ ssq_t,
    const float* __restrict__ g_z, const float* __restrict__ b_z,
    const float* __restrict__ g_t, const float* __restrict__ b_t,
    float* __restrict__ sz_s, float* __restrict__ sz_t,
    float* __restrict__ st_s, float* __restrict__ st_t) {
  int h = blockIdx.x * 256 + threadIdx.x;
  if (h >= H_N) return;
  {
    float m = sum_z[h] * (1.f / B_N);
    float v = ssq_z[h] * (1.f / B_N) - m * m;
    float s = g_z[h] * rsqrtf(v + BN_EPS);
    sz_s[h] = s;
    sz_t[h] = b_z[h] - m * s;
  }
  {
    float m = sum_t[h] * (1.f / (B_N * L_N));
    float v = ssq_t[h] * (1.f / (B_N * L_N)) - m * m;
    float s = g_t[h] * rsqrtf(v + BN_EPS);
    st_s[h] = s;
    st_t[h] = b_t[h] - m * s;
  }
}

// ---------- K3b: fold BN scale into cls_W (bf16) + folded bias ----------
__global__ __launch_bounds__(256) void prep_cls_kernel(
    const float* __restrict__ W, const float* __restrict__ szs,
    const float* __restrict__ szt, const float* __restrict__ bias,
    __hip_bfloat16* __restrict__ Wb, float* __restrict__ cprime) {
  __shared__ float sbuf[4];
  int n = blockIdx.x;
  int t = threadIdx.x;
  float dot = 0.f;
  if (t < 192) {
    int c4 = t * 4;
    const float* row = W + (size_t)n * H_N;
    float4 w4 = *(const float4*)(row + c4);
    float4 s4 = *(const float4*)(szs + c4);
    float4 t4 = *(const float4*)(szt + c4);
    store_bf16x4(Wb + (size_t)n * H_N + c4,
                 make_float4(w4.x * s4.x, w4.y * s4.y, w4.z * s4.z, w4.w * s4.w));
    dot = w4.x * t4.x + w4.y * t4.y + w4.z * t4.z + w4.w * t4.w;
  }
  float s = block_reduce_sum256(dot, sbuf);
  if (t == 0) cprime[n] = s + bias[n];
}

// ---------- K3c: WlT[k][n] = bf16(label_W[n][k]) ----------
__global__ __launch_bounds__(256) void transpose_wl_kernel(
    const float* __restrict__ Wl, __hip_bfloat16* __restrict__ WlT) {
  __shared__ float tile[32][33];
  int t = threadIdx.x;
  int tx = t & 31, ty0 = t >> 5;
  int n0 = blockIdx.x * 32, k0 = blockIdx.y * 32;
#pragma unroll
  for (int p = 0; p < 4; ++p)
    tile[ty0 + p * 8][tx] = Wl[(size_t)(n0 + ty0 + p * 8) * H_N + k0 + tx];
  __syncthreads();
#pragma unroll
  for (int p = 0; p < 4; ++p) {
    unsigned short us = bf16b(tile[tx][ty0 + p * 8]);
    *((unsigned short*)WlT + (size_t)(k0 + ty0 + p * 8) * H_N + n0 + tx) = us;
  }
}

// ---------- K4/K5: 128x128 bf16 MFMA GEMM template ----------
template <bool WRITE_BF16, bool HAS_BIAS>
__global__ __launch_bounds__(256) void gemm128_kernel(
    const __hip_bfloat16* __restrict__ A, const __hip_bfloat16* __restrict__ Bm,
    const float* __restrict__ bias, float* __restrict__ outF,
    __hip_bfloat16* __restrict__ outB) {
  __shared__ __align__(16) __hip_bfloat16 Asm[128 * 32];
  __shared__ __align__(16) __hip_bfloat16 Bsm[128 * 32];
  int tid = threadIdx.x, lane = tid & 63, wid = tid >> 6;
  int wr = wid >> 1, wc = wid & 1;
  int i0 = blockIdx.x * 128, n0 = blockIdx.y * 128;
  int llo = lane & 15, lhi = lane >> 4;
  f32x4 acc[4][4] = {};
  for (int k0 = 0; k0 < H_N; k0 += 32) {
#pragma unroll
    for (int r = 0; r < 2; ++r) {
      int s = r * 256 + wid * 64 + lane;
      int row = s >> 2, kc = (s & 3) * 8;
      size_t go = (size_t)row * H_N + k0 + kc;
      async_copy16((char*)Asm + (size_t)(r * 256 + wid * 64) * 16,
                   A + (size_t)i0 * H_N + go);
      async_copy16((char*)Bsm + (size_t)(r * 256 + wid * 64) * 16,
                   Bm + (size_t)n0 * H_N + go);
    }
    __syncthreads();
    short8 a[4], b[4];
#pragma unroll
    for (int m = 0; m < 4; ++m)
      a[m] = *(const short8*)((const char*)Asm +
                              ((wr * 64 + m * 16 + llo) * 32 + lhi * 8) * 2);
#pragma unroll
    for (int n = 0; n < 4; ++n)
      b[n] = *(const short8*)((const char*)Bsm +
                              ((wc * 64 + n * 16 + llo) * 32 + lhi * 8) * 2);
#pragma unroll
    for (int m = 0; m < 4; ++m)
#pragma unroll
      for (int n = 0; n < 4; ++n)
        acc[m][n] =
            __builtin_amdgcn_mfma_f32_16x16x32_bf16(a[m], b[n], acc[m][n], 0, 0, 0);
    __syncthreads();
  }
#pragma unroll
  for (int n = 0; n < 4; ++n) {
    int col = n0 + wc * 64 + n * 16 + llo;
    float bv = HAS_BIAS ? bias[col] : 0.f;
#pragma unroll
    for (int m = 0; m < 4; ++m) {
#pragma unroll
      for (int r = 0; r < 4; ++r) {
        int row = i0 + wr * 64 + m * 16 + lhi * 4 + r;
        float val = acc[m][n][r] + bv;
        outF[(size_t)row * H_N + col] = val;
        if (WRITE_BF16)
          outB[(size_t)row * H_N + col] = __float2bfloat16(val);
      }
    }
  }
}

// ---------- K6: logits ----------
__global__ __launch_bounds__(256) void logits_kernel(
    const float* __restrict__ seq, const float* __restrict__ u,
    const float* __restrict__ zp, const float* __restrict__ st_s,
    const float* __restrict__ st_t, const float* __restrict__ label_b,
    float* __restrict__ out) {
  __shared__ float sbuf[4];
  int b = blockIdx.x;
  int t = threadIdx.x;
  bool act = t < 192;
  int c4 = t * 4;
  float4 w4 = make_float4(0.f, 0.f, 0.f, 0.f);
  float apart = 0.f;
  if (act) {
    float4 u4 = *(const float4*)(u + (size_t)b * H_N + c4);
    float4 zp4 = *(const float4*)(zp + (size_t)b * H_N + c4);
    float4 ss4 = *(const float4*)(st_s + c4);
    float4 tt4 = *(const float4*)(st_t + c4);
    float4 lb4 = *(const float4*)(label_b + c4);
    w4 = make_float4(u4.x * ss4.x, u4.y * ss4.y, u4.z * ss4.z, u4.w * ss4.w);
    apart = u4.x * tt4.x + u4.y * tt4.y + u4.z * tt4.z + u4.w * tt4.w +
            zp4.x * lb4.x + zp4.y * lb4.y + zp4.z * lb4.z + zp4.w * lb4.w;
  }
  float alpha = block_reduce_sum256(apart, sbuf);
  const float* base = seq + (size_t)b * (S_N * H_N);
#pragma unroll
  for (int l = 0; l < L_N; ++l) {
    float part = 0.f;
    if (act) {
      float4 v4;
      if (l == 0) {
        float4 a4 = *(const float4*)(base + H_N + c4);
        float4 b4 = *(const float4*)(base + 2 * H_N + c4);
        v4 = make_float4(0.5f * (a4.x + b4.x), 0.5f * (a4.y + b4.y),
                         0.5f * (a4.z + b4.z), 0.5f * (a4.w + b4.w));
      } else {
        v4 = *(const float4*)(base + (size_t)(l + 2) * H_N + c4);
      }
      part = v4.x * w4.x + v4.y * w4.y + v4.z * w4.z + v4.w * w4.w;
    }
    float s = block_reduce_sum256(part, sbuf);
    if (t == 0) out[b * L_N + l] = s + alpha;
  }
}

// ---------- K7: 256x256 8-wave bf16 MFMA GEMM (R5 structure) ----------
// DIAGNOSTIC ROUND: grid duplicated 2x (dup half writes to dummy scratch) so
// this dispatch exceeds the harness poison fills and surfaces in rocprof top-5
// with full counters (VGPR spill? LDS conflicts? MfmaUtil?). Also adds the
// bijective XCD-pair swizzle: xcd=fid&7 keeps 2 A-panels L2-resident per XCD.
#define NT_K 12  // 768 / 64
__global__ __launch_bounds__(512, 1) void sgemm_fused_kernel(
    const __hip_bfloat16* __restrict__ zb, const __hip_bfloat16* __restrict__ tb,
    const float* __restrict__ zn_inv, const float* __restrict__ thn_inv,
    const int* __restrict__ labels, float* __restrict__ pos_z,
    float* __restrict__ neg_z, float* __restrict__ pos_t,
    float* __restrict__ neg_t, float* __restrict__ dummy) {
  __shared__ __align__(128) char ldsbuf[2][65536];  // per buf: A 32KB | B 32KB

  const int tid = threadIdx.x;
  const int lane = tid & 63, wid = tid >> 6;
  const int llo = lane & 15, lhi = lane >> 4;
  const int wrbase = (wid >> 2) * 128;  // 2 wave-rows
  const int wcbase = (wid & 3) * 64;    // 4 wave-cols

  // XCD-pair swizzle + 2x duplication (dup interleaved so L2 behavior ~real)
  int fid = blockIdx.x;
  int xcd = fid & 7;
  int s0 = fid >> 3;       // 0..319
  int dup = s0 & 1;
  int s2 = s0 >> 1;        // 0..159
  int xt = xcd * 2 + (s2 & 1), yt = s2 >> 1;
  const int i0 = xt * 256, n0 = yt * 256;
  float* o_pz = dup ? (dummy + 0) : pos_z;
  float* o_nz = dup ? (dummy + 4096) : neg_z;
  float* o_pt = dup ? (dummy + 8192) : pos_t;
  float* o_nt = dup ? (dummy + 12288) : neg_t;

  f32x4 acc[8][4] = {};

  // stage row-part p (64 rows x 64 k) of K-tile kt for A and B into buffer c
  auto stagePart = [&](int c, int kt, int p) {
    int s = p * 512 + tid;
    int row = s >> 3;                // 8 x 16B slots per 128B row
    int lq = (s & 7) ^ (row & 7);    // inverse swizzle on global source
    int kofs = kt * 64 + lq * 8;
    int wub = (p * 512 + wid * 64) * 16;  // wave-uniform LDS base
    async_copy16(&ldsbuf[c][0] + wub, zb + (size_t)(i0 + row) * H_N + kofs);
    async_copy16(&ldsbuf[c][32768] + wub, tb + (size_t)(n0 + row) * H_N + kofs);
  };

  // prologue: stage K-tile 0 fully, drain, publish
#pragma unroll
  for (int p = 0; p < 4; ++p) stagePart(0, 0, p);
  asm volatile("s_waitcnt vmcnt(0)" ::: "memory");
  __builtin_amdgcn_s_barrier();

  for (int t = 0; t < NT_K; ++t) {
    const char* ldsA = &ldsbuf[t & 1][0];
    const char* ldsB = &ldsbuf[t & 1][32768];
#pragma unroll
    for (int p = 0; p < 4; ++p) {
      const int kk = p >> 1, mh = (p & 1) * 4;
      const int slot = ((kk * 4 + lhi) ^ (llo & 7)) * 16;  // swizzled read
      short8 a[4], b[4];
#pragma unroll
      for (int m = 0; m < 4; ++m) {
        int row = wrbase + (mh + m) * 16 + llo;
        a[m] = *(const short8*)(ldsA + row * 128 + slot);
      }
#pragma unroll
      for (int n = 0; n < 4; ++n) {
        int col = wcbase + n * 16 + llo;
        b[n] = *(const short8*)(ldsB + col * 128 + slot);
      }
      if (t + 1 < NT_K) stagePart((t + 1) & 1, t + 1, p);  // fly across phases
      __builtin_amdgcn_s_barrier();
      asm volatile("s_waitcnt lgkmcnt(0)" ::: "memory");
      __builtin_amdgcn_sched_barrier(0);  // rule #18: pin MFMA below the wait
      __builtin_amdgcn_s_setprio(1);
#pragma unroll
      for (int m = 0; m < 4; ++m)
#pragma unroll
        for (int n = 0; n < 4; ++n)
          acc[mh + m][n] = __builtin_amdgcn_mfma_f32_16x16x32_bf16(
              a[m], b[n], acc[mh + m][n], 0, 0, 0);
      __builtin_amdgcn_s_setprio(0);
      if (p == 3)  // K-tile boundary: next tile must be resident after barrier
        asm volatile("s_waitcnt vmcnt(0)" ::: "memory");
      __builtin_amdgcn_s_barrier();
    }
  }
  __syncthreads();  // full fence before overlaying epilogue arrays onto ldsbuf

  // ---- fused epilogue: exp + masks + row/col reductions (LDS overlay) ----
  float* rpos = (float*)&ldsbuf[0][0];
  float* rneg = rpos + 256;
  float* cpos = rneg + 256;
  float* cneg = cpos + 256;
  float* rnorm = cneg + 256;
  float* cnorm = rnorm + 256;
  int* rowlab = (int*)(cnorm + 256);
  int* colj = rowlab + 256;
  int* coll = colj + 256;
  int* collab = coll + 256;

  if (tid < 256) {
    rowlab[tid] = labels[i0 + tid];
    rnorm[tid] = zn_inv[i0 + tid] * TEMP_INV;
    int c = n0 + tid;
    int j = c / 5;
    colj[tid] = j;
    coll[tid] = c - j * 5;
    collab[tid] = labels[j];
    cnorm[tid] = thn_inv[c];
    rpos[tid] = 0.f; rneg[tid] = 0.f; cpos[tid] = 0.f; cneg[tid] = 0.f;
  }
  __syncthreads();

  int cl[4], jg[4], lv[4], lj[4];
  float cs[4];
#pragma unroll
  for (int ni = 0; ni < 4; ++ni) {
    cl[ni] = wcbase + ni * 16 + llo;
    jg[ni] = colj[cl[ni]];
    lv[ni] = coll[cl[ni]];
    lj[ni] = collab[cl[ni]];
    cs[ni] = cnorm[cl[ni]];
  }
  float cpAcc[4] = {}, cnAcc[4] = {};
#pragma unroll
  for (int mi = 0; mi < 8; ++mi) {
#pragma unroll
    for (int r = 0; r < 4; ++r) {
      int rl = wrbase + mi * 16 + lhi * 4 + r;
      int ig = i0 + rl;
      int li = rowlab[rl];
      float rscale = rnorm[rl];
      float rp = 0.f, rn = 0.f;
#pragma unroll
      for (int ni = 0; ni < 4; ++ni) {
        float e = __expf(acc[mi][ni][r] * rscale * cs[ni]);
        bool same = (li == lj[ni]);
        bool diag = (ig == jg[ni]);
        if (same) {
          if (!diag && lv[ni] == li) { rp += e; cpAcc[ni] += e; }
        } else {
          rn += e;
          if (lv[ni] == lj[ni]) cnAcc[ni] += e;
        }
      }
      if (rp != 0.f) atomicAdd(&rpos[rl], rp);
      if (rn != 0.f) atomicAdd(&rneg[rl], rn);
    }
  }
#pragma unroll
  for (int ni = 0; ni < 4; ++ni) {
    if (cpAcc[ni] != 0.f) atomicAdd(&cpos[cl[ni]], cpAcc[ni]);
    if (cnAcc[ni] != 0.f) atomicAdd(&cneg[cl[ni]], cnAcc[ni]);
  }
  __syncthreads();
  if (tid < 256) {
    float v;
    v = rpos[tid]; if (v != 0.f) atomicAdd(&o_pz[i0 + tid], v);
    v = rneg[tid]; if (v != 0.f) atomicAdd(&o_nz[i0 + tid], v);
    int j = colj[tid];
    v = cpos[tid]; if (v != 0.f) atomicAdd(&o_pt[j], v);
    v = cneg[tid]; if (v != 0.f) atomicAdd(&o_nt[j], v);
  }
}

// ---------- K8: final loss ----------
__global__ __launch_bounds__(256) void loss_kernel(
    const float* __restrict__ pos_z, const float* __restrict__ neg_z,
    const float* __restrict__ pos_t, const float* __restrict__ neg_t,
    const int* __restrict__ labels, const int* __restrict__ cnt,
    float* __restrict__ out_loss) {
  __shared__ float sbuf[4];
  int i = blockIdx.x * 256 + threadIdx.x;
  float term = 0.f;
  int li = labels[i];
  if (cnt[li] > 1) {
    float pz = pos_z[i], nz = neg_z[i];
    float pt = pos_t[i], nt = neg_t[i];
    term = -logf(pz / (pz + nz + 1e-8f)) - logf(pt / (pt + nt + 1e-8f));
  }
  float s = block_reduce_sum256(term, sbuf);
  if (threadIdx.x == 0) atomicAdd(out_loss, s * (1.0f / B_N));
}

// ---------- launch ----------
extern "C" void kernel_launch(void* const* d_in, const int* in_sizes, int n_in,
                              void* d_out, int out_size, void* d_ws, size_t ws_size,
                              hipStream_t stream) {
  const float* seq = (const float*)d_in[0];
  const float* cls_gamma = (const float*)d_in[1];
  const float* cls_beta = (const float*)d_in[2];
  const float* cls_W = (const float*)d_in[3];
  const float* cls_b = (const float*)d_in[4];
  const float* label_gamma = (const float*)d_in[5];
  const float* label_beta = (const float*)d_in[6];
  const float* label_W = (const float*)d_in[7];
  const float* label_b = (const float*)d_in[8];
  const int* labels = (const int*)d_in[9];
  float* out = (float*)d_out;
  float* ws = (float*)d_ws;

  constexpr size_t OFF_SUMZ = 0;
  constexpr size_t OFF_SSQZ = 768;
  constexpr size_t OFF_SUMT = 1536;
  constexpr size_t OFF_SSQT = 2304;
  constexpr size_t OFF_POSZ = 3072;
  constexpr size_t OFF_NEGZ = 7168;
  constexpr size_t OFF_POST = 11264;
  constexpr size_t OFF_NEGT = 15360;
  constexpr size_t OFF_CNT = 19456;  // 8 ints
  constexpr size_t ZERO_FLOATS = 19464;
  constexpr size_t OFF_SZS = 19464;
  constexpr size_t OFF_SZT = 20232;
  constexpr size_t OFF_STS = 21000;
  constexpr size_t OFF_STT = 21768;
  constexpr size_t OFF_ZNI = 22536;     // 4096
  constexpr size_t OFF_TNI = 26632;     // 20480
  constexpr size_t OFF_CPRIME = 47112;  // 768
  constexpr size_t OFF_ZP = 47880;      // 4096*768 fp32
  constexpr size_t OFF_U = OFF_ZP + (size_t)B_N * H_N;
  constexpr size_t F32_END = OFF_U + (size_t)B_N * H_N;
  constexpr size_t BYTE_ZB = F32_END * sizeof(float);
  constexpr size_t BYTE_TB = BYTE_ZB + (size_t)B_N * H_N * 2;
  constexpr size_t BYTE_ZPB = BYTE_TB + (size_t)B_N * L_N * H_N * 2;
  constexpr size_t BYTE_WCB = BYTE_ZPB + (size_t)B_N * H_N * 2;
  constexpr size_t BYTE_WLT = BYTE_WCB + (size_t)H_N * H_N * 2;
  constexpr size_t BYTE_DUMMY = BYTE_WLT + (size_t)H_N * H_N * 2;  // 16-aligned
  constexpr size_t TOTAL_BYTES = BYTE_DUMMY + 16384 * sizeof(float);
  if (ws_size < TOTAL_BYTES) return;

  __hip_bfloat16* zb = (__hip_bfloat16*)((char*)d_ws + BYTE_ZB);
  __hip_bfloat16* tb = (__hip_bfloat16*)((char*)d_ws + BYTE_TB);
  __hip_bfloat16* zpb = (__hip_bfloat16*)((char*)d_ws + BYTE_ZPB);
  __hip_bfloat16* wcb = (__hip_bfloat16*)((char*)d_ws + BYTE_WCB);
  __hip_bfloat16* wlt = (__hip_bfloat16*)((char*)d_ws + BYTE_WLT);
  float* dummy = (float*)((char*)d_ws + BYTE_DUMMY);

  hipMemsetAsync(d_ws, 0, ZERO_FLOATS * sizeof(float), stream);
  hipMemsetAsync((char*)d_out + (size_t)B_N * L_N * sizeof(float), 0, sizeof(float),
                 stream);

  extract_kernel<<<512, 256, 0, stream>>>(seq, zb, tb, ws + OFF_ZNI, ws + OFF_TNI,
                                          ws + OFF_SUMZ, ws + OFF_SSQZ,
                                          ws + OFF_SUMT, ws + OFF_SSQT);
  count_kernel<<<16, 256, 0, stream>>>(labels, (int*)(ws + OFF_CNT));
  finalize_kernel<<<3, 256, 0, stream>>>(
      ws + OFF_SUMZ, ws + OFF_SSQZ, ws + OFF_SUMT, ws + OFF_SSQT, cls_gamma,
      cls_beta, label_gamma, label_beta, ws + OFF_SZS, ws + OFF_SZT, ws + OFF_STS,
      ws + OFF_STT);
  prep_cls_kernel<<<H_N, 256, 0, stream>>>(cls_W, ws + OFF_SZS, ws + OFF_SZT, cls_b,
                                           wcb, ws + OFF_CPRIME);
  transpose_wl_kernel<<<dim3(24, 24), 256, 0, stream>>>(label_W, wlt);
  gemm128_kernel<true, true><<<dim3(32, 6), 256, 0, stream>>>(
      zb, wcb, ws + OFF_CPRIME, ws + OFF_ZP, zpb);
  gemm128_kernel<false, false><<<dim3(32, 6), 256, 0, stream>>>(
      zpb, wlt, nullptr, ws + OFF_U, nullptr);
  logits_kernel<<<B_N, 256, 0, stream>>>(seq, ws + OFF_U, ws + OFF_ZP, ws + OFF_STS,
                                         ws + OFF_STT, label_b, out);
  sgemm_fused_kernel<<<2560, 512, 0, stream>>>(
      zb, tb, ws + OFF_ZNI, ws + OFF_TNI, labels, ws + OFF_POSZ, ws + OFF_NEGZ,
      ws + OFF_POST, ws + OFF_NEGT, dummy);
  loss_kernel<<<16, 256, 0, stream>>>(ws + OFF_POSZ, ws + OFF_NEGZ, ws + OFF_POST,
                                      ws + OFF_NEGT, labels,
                                      (const int*)(ws + OFF_CNT),
                                      out + (size_t)B_N * L_N);
}

// Round 8
// 461.130 us; speedup vs baseline: 1.6003x; 1.6003x over previous
//
#include <hip/hip_runtime.h>
#include <hip/hip_bf16.h>
#include <cstdint>
#include <cstddef>

#define B_N 4096
#define S_N 64
#define H_N 768
#define L_N 5
#define TEMP_INV (1.0f / 0.07f)
#define BN_EPS 1e-5f

typedef __attribute__((ext_vector_type(8))) short short8;
typedef __attribute__((ext_vector_type(4))) float f32x4;

// ---------- async global->LDS 16B ----------
__device__ __forceinline__ void async_copy16(void* lds, const void* g) {
  __builtin_amdgcn_global_load_lds(
      (const __attribute__((address_space(1))) unsigned int*)g,
      (__attribute__((address_space(3))) unsigned int*)lds, 16, 0, 0);
}

__device__ __forceinline__ unsigned short bf16b(float x) {
  __hip_bfloat16 h = __float2bfloat16(x);
  return *reinterpret_cast<unsigned short*>(&h);
}
__device__ __forceinline__ void store_bf16x4(void* p, float4 v) {
  ushort4 o = make_ushort4(bf16b(v.x), bf16b(v.y), bf16b(v.z), bf16b(v.w));
  *reinterpret_cast<ushort4*>(p) = o;
}

// ---------- block reduction (256 threads = 4 waves) ----------
__device__ inline float block_reduce_sum256(float v, float* sbuf) {
#pragma unroll
  for (int off = 32; off > 0; off >>= 1) v += __shfl_down(v, off, 64);
  int lane = threadIdx.x & 63;
  int wid = threadIdx.x >> 6;
  __syncthreads();
  if (lane == 0) sbuf[wid] = v;
  __syncthreads();
  float r = 0.f;
  if (threadIdx.x == 0) r = sbuf[0] + sbuf[1] + sbuf[2] + sbuf[3];
  return r;  // valid on thread 0 only
}

// ---------- K1: fused extract + row norms + column stats (single seq pass) ----------
__global__ __launch_bounds__(256) void extract_kernel(
    const float* __restrict__ seq, __hip_bfloat16* __restrict__ zb,
    __hip_bfloat16* __restrict__ tb, float* __restrict__ zn_inv,
    float* __restrict__ thn_inv, float* __restrict__ sum_z,
    float* __restrict__ ssq_z, float* __restrict__ sum_t,
    float* __restrict__ ssq_t) {
  __shared__ float pr[8][6][3];  // row, {z,l0..l4}, wave
  int t = threadIdx.x;
  int wv = t >> 6, ln = t & 63;
  bool act = t < 192;
  int c4 = t * 4;
  int b0 = blockIdx.x * 8;
  float zs[4] = {}, zq[4] = {}, ts4[4] = {}, tq4[4] = {};
  for (int r = 0; r < 8; ++r) {
    int b = b0 + r;
    const float* base = seq + (size_t)b * (S_N * H_N);
    float pv[6] = {0.f, 0.f, 0.f, 0.f, 0.f, 0.f};
    if (act) {
      float4 z4 = *(const float4*)(base + c4);
      store_bf16x4(zb + (size_t)b * H_N + c4, z4);
      pv[0] = z4.x * z4.x + z4.y * z4.y + z4.z * z4.z + z4.w * z4.w;
      zs[0] += z4.x; zs[1] += z4.y; zs[2] += z4.z; zs[3] += z4.w;
      zq[0] += z4.x * z4.x; zq[1] += z4.y * z4.y;
      zq[2] += z4.z * z4.z; zq[3] += z4.w * z4.w;
#pragma unroll
      for (int l = 0; l < L_N; ++l) {
        float4 v4;
        if (l == 0) {
          float4 a4 = *(const float4*)(base + H_N + c4);
          float4 b4 = *(const float4*)(base + 2 * H_N + c4);
          v4 = make_float4(0.5f * (a4.x + b4.x), 0.5f * (a4.y + b4.y),
                           0.5f * (a4.z + b4.z), 0.5f * (a4.w + b4.w));
        } else {
          v4 = *(const float4*)(base + (size_t)(l + 2) * H_N + c4);
        }
        store_bf16x4(tb + ((size_t)b * L_N + l) * H_N + c4, v4);
        pv[1 + l] = v4.x * v4.x + v4.y * v4.y + v4.z * v4.z + v4.w * v4.w;
        ts4[0] += v4.x; ts4[1] += v4.y; ts4[2] += v4.z; ts4[3] += v4.w;
        tq4[0] += v4.x * v4.x; tq4[1] += v4.y * v4.y;
        tq4[2] += v4.z * v4.z; tq4[3] += v4.w * v4.w;
      }
    }
#pragma unroll
    for (int v = 0; v < 6; ++v) {
      float x = pv[v];
#pragma unroll
      for (int off = 32; off > 0; off >>= 1) x += __shfl_down(x, off, 64);
      if (ln == 0 && wv < 3) pr[r][v][wv] = x;
    }
  }
  __syncthreads();
  if (t < 48) {
    int r = t / 6, v = t - r * 6;
    float s = pr[r][v][0] + pr[r][v][1] + pr[r][v][2];
    float inv = 1.f / fmaxf(sqrtf(s), 1e-12f);
    int b = b0 + r;
    if (v == 0) zn_inv[b] = inv;
    else thn_inv[b * L_N + (v - 1)] = inv;
  }
  if (act) {
#pragma unroll
    for (int j = 0; j < 4; ++j) {
      atomicAdd(&sum_z[c4 + j], zs[j]);
      atomicAdd(&ssq_z[c4 + j], zq[j]);
      atomicAdd(&sum_t[c4 + j], ts4[j]);
      atomicAdd(&ssq_t[c4 + j], tq4[j]);
    }
  }
}

// ---------- label histogram ----------
__global__ void count_kernel(const int* __restrict__ labels, int* __restrict__ cnt) {
  int i = blockIdx.x * 256 + threadIdx.x;
  if (i < B_N) atomicAdd(&cnt[labels[i]], 1);
}

// ---------- K3: bn affine coefficients ----------
__global__ void finalize_kernel(
    const float* __restrict__ sum_z, const float* __restrict__ ssq_z,
    const float* __restrict__ sum_t, const float* __restrict__ ssq_t,
    const float* __restrict__ g_z, const float* __restrict__ b_z,
    const float* __restrict__ g_t, const float* __restrict__ b_t,
    float* __restrict__ sz_s, float* __restrict__ sz_t,
    float* __restrict__ st_s, float* __restrict__ st_t) {
  int h = blockIdx.x * 256 + threadIdx.x;
  if (h >= H_N) return;
  {
    float m = sum_z[h] * (1.f / B_N);
    float v = ssq_z[h] * (1.f / B_N) - m * m;
    float s = g_z[h] * rsqrtf(v + BN_EPS);
    sz_s[h] = s;
    sz_t[h] = b_z[h] - m * s;
  }
  {
    float m = sum_t[h] * (1.f / (B_N * L_N));
    float v = ssq_t[h] * (1.f / (B_N * L_N)) - m * m;
    float s = g_t[h] * rsqrtf(v + BN_EPS);
    st_s[h] = s;
    st_t[h] = b_t[h] - m * s;
  }
}

// ---------- K3b: fold BN scale into cls_W (bf16) + folded bias ----------
__global__ __launch_bounds__(256) void prep_cls_kernel(
    const float* __restrict__ W, const float* __restrict__ szs,
    const float* __restrict__ szt, const float* __restrict__ bias,
    __hip_bfloat16* __restrict__ Wb, float* __restrict__ cprime) {
  __shared__ float sbuf[4];
  int n = blockIdx.x;
  int t = threadIdx.x;
  float dot = 0.f;
  if (t < 192) {
    int c4 = t * 4;
    const float* row = W + (size_t)n * H_N;
    float4 w4 = *(const float4*)(row + c4);
    float4 s4 = *(const float4*)(szs + c4);
    float4 t4 = *(const float4*)(szt + c4);
    store_bf16x4(Wb + (size_t)n * H_N + c4,
                 make_float4(w4.x * s4.x, w4.y * s4.y, w4.z * s4.z, w4.w * s4.w));
    dot = w4.x * t4.x + w4.y * t4.y + w4.z * t4.z + w4.w * t4.w;
  }
  float s = block_reduce_sum256(dot, sbuf);
  if (t == 0) cprime[n] = s + bias[n];
}

// ---------- K3c: WlT[k][n] = bf16(label_W[n][k]) ----------
__global__ __launch_bounds__(256) void transpose_wl_kernel(
    const float* __restrict__ Wl, __hip_bfloat16* __restrict__ WlT) {
  __shared__ float tile[32][33];
  int t = threadIdx.x;
  int tx = t & 31, ty0 = t >> 5;
  int n0 = blockIdx.x * 32, k0 = blockIdx.y * 32;
#pragma unroll
  for (int p = 0; p < 4; ++p)
    tile[ty0 + p * 8][tx] = Wl[(size_t)(n0 + ty0 + p * 8) * H_N + k0 + tx];
  __syncthreads();
#pragma unroll
  for (int p = 0; p < 4; ++p) {
    unsigned short us = bf16b(tile[tx][ty0 + p * 8]);
    *((unsigned short*)WlT + (size_t)(k0 + ty0 + p * 8) * H_N + n0 + tx) = us;
  }
}

// ---------- K4/K5: 128x128 bf16 MFMA GEMM template ----------
template <bool WRITE_BF16, bool HAS_BIAS>
__global__ __launch_bounds__(256) void gemm128_kernel(
    const __hip_bfloat16* __restrict__ A, const __hip_bfloat16* __restrict__ Bm,
    const float* __restrict__ bias, float* __restrict__ outF,
    __hip_bfloat16* __restrict__ outB) {
  __shared__ __align__(16) __hip_bfloat16 Asm[128 * 32];
  __shared__ __align__(16) __hip_bfloat16 Bsm[128 * 32];
  int tid = threadIdx.x, lane = tid & 63, wid = tid >> 6;
  int wr = wid >> 1, wc = wid & 1;
  int i0 = blockIdx.x * 128, n0 = blockIdx.y * 128;
  int llo = lane & 15, lhi = lane >> 4;
  f32x4 acc[4][4] = {};
  for (int k0 = 0; k0 < H_N; k0 += 32) {
#pragma unroll
    for (int r = 0; r < 2; ++r) {
      int s = r * 256 + wid * 64 + lane;
      int row = s >> 2, kc = (s & 3) * 8;
      size_t go = (size_t)row * H_N + k0 + kc;
      async_copy16((char*)Asm + (size_t)(r * 256 + wid * 64) * 16,
                   A + (size_t)i0 * H_N + go);
      async_copy16((char*)Bsm + (size_t)(r * 256 + wid * 64) * 16,
                   Bm + (size_t)n0 * H_N + go);
    }
    __syncthreads();
    short8 a[4], b[4];
#pragma unroll
    for (int m = 0; m < 4; ++m)
      a[m] = *(const short8*)((const char*)Asm +
                              ((wr * 64 + m * 16 + llo) * 32 + lhi * 8) * 2);
#pragma unroll
    for (int n = 0; n < 4; ++n)
      b[n] = *(const short8*)((const char*)Bsm +
                              ((wc * 64 + n * 16 + llo) * 32 + lhi * 8) * 2);
#pragma unroll
    for (int m = 0; m < 4; ++m)
#pragma unroll
      for (int n = 0; n < 4; ++n)
        acc[m][n] =
            __builtin_amdgcn_mfma_f32_16x16x32_bf16(a[m], b[n], acc[m][n], 0, 0, 0);
    __syncthreads();
  }
#pragma unroll
  for (int n = 0; n < 4; ++n) {
    int col = n0 + wc * 64 + n * 16 + llo;
    float bv = HAS_BIAS ? bias[col] : 0.f;
#pragma unroll
    for (int m = 0; m < 4; ++m) {
#pragma unroll
      for (int r = 0; r < 4; ++r) {
        int row = i0 + wr * 64 + m * 16 + lhi * 4 + r;
        float val = acc[m][n][r] + bv;
        outF[(size_t)row * H_N + col] = val;
        if (WRITE_BF16)
          outB[(size_t)row * H_N + col] = __float2bfloat16(val);
      }
    }
  }
}

// ---------- K6: logits ----------
__global__ __launch_bounds__(256) void logits_kernel(
    const float* __restrict__ seq, const float* __restrict__ u,
    const float* __restrict__ zp, const float* __restrict__ st_s,
    const float* __restrict__ st_t, const float* __restrict__ label_b,
    float* __restrict__ out) {
  __shared__ float sbuf[4];
  int b = blockIdx.x;
  int t = threadIdx.x;
  bool act = t < 192;
  int c4 = t * 4;
  float4 w4 = make_float4(0.f, 0.f, 0.f, 0.f);
  float apart = 0.f;
  if (act) {
    float4 u4 = *(const float4*)(u + (size_t)b * H_N + c4);
    float4 zp4 = *(const float4*)(zp + (size_t)b * H_N + c4);
    float4 ss4 = *(const float4*)(st_s + c4);
    float4 tt4 = *(const float4*)(st_t + c4);
    float4 lb4 = *(const float4*)(label_b + c4);
    w4 = make_float4(u4.x * ss4.x, u4.y * ss4.y, u4.z * ss4.z, u4.w * ss4.w);
    apart = u4.x * tt4.x + u4.y * tt4.y + u4.z * tt4.z + u4.w * tt4.w +
            zp4.x * lb4.x + zp4.y * lb4.y + zp4.z * lb4.z + zp4.w * lb4.w;
  }
  float alpha = block_reduce_sum256(apart, sbuf);
  const float* base = seq + (size_t)b * (S_N * H_N);
#pragma unroll
  for (int l = 0; l < L_N; ++l) {
    float part = 0.f;
    if (act) {
      float4 v4;
      if (l == 0) {
        float4 a4 = *(const float4*)(base + H_N + c4);
        float4 b4 = *(const float4*)(base + 2 * H_N + c4);
        v4 = make_float4(0.5f * (a4.x + b4.x), 0.5f * (a4.y + b4.y),
                         0.5f * (a4.z + b4.z), 0.5f * (a4.w + b4.w));
      } else {
        v4 = *(const float4*)(base + (size_t)(l + 2) * H_N + c4);
      }
      part = v4.x * w4.x + v4.y * w4.y + v4.z * w4.z + v4.w * w4.w;
    }
    float s = block_reduce_sum256(part, sbuf);
    if (t == 0) out[b * L_N + l] = s + alpha;
  }
}

// ---------- K7: 128x128 4-wave bf16 MFMA GEMM, dbuf BK=32, 3 blocks/CU ----------
// R7 diagnosis: 256^2 8-wave was pinned at 2 waves/SIMD (regs+LDS) -> MfmaUtil
// 18.5%, everything latency-exposed. This config: acc 64 + ~70 VGPR -> 3
// waves/SIMD via __launch_bounds__(256,3); LDS 2x16KB -> 3 blocks/CU (96KB).
// 12 waves/CU of inter-block TLP hide barrier/vmcnt/LDS-queue latency.
// LDS rows pair-packed to keep the PROVEN zero-conflict 128B-row swizzle
// (R7: SQ_LDS_BANK_CONFLICT=0): LDS row R = logical rows {2R,2R+1};
// slot' = slot ^ (R&7); inverse applied on global source (rule #21).
#define NT_K 24  // 768 / 32
__global__ __launch_bounds__(256, 3) void sgemm_fused_kernel(
    const __hip_bfloat16* __restrict__ zb, const __hip_bfloat16* __restrict__ tb,
    const float* __restrict__ zn_inv, const float* __restrict__ thn_inv,
    const int* __restrict__ labels, float* __restrict__ pos_z,
    float* __restrict__ neg_z, float* __restrict__ pos_t,
    float* __restrict__ neg_t) {
  __shared__ __align__(128) char ldsbuf[2][16384];  // per buf: A 8KB | B 8KB

  const int tid = threadIdx.x;
  const int lane = tid & 63, wid = tid >> 6;
  const int llo = lane & 15, lhi = lane >> 4;
  const int wr = wid >> 1, wc = wid & 1;
  // bijective XCD swizzle: 32 = 8 xcd * 4
  const int xcd = blockIdx.x & 7;
  const int s0 = blockIdx.x >> 3;  // 0..639
  const int i0 = (xcd * 4 + (s0 & 3)) * 128;
  const int n0 = (s0 >> 2) * 128;

  f32x4 acc[4][4] = {};

  // stage K-tile kt into buffer c (4 loads/thread: 2 A + 2 B)
  auto stage = [&](int c, int kt) {
#pragma unroll
    for (int h = 0; h < 2; ++h) {
      int s = h * 256 + tid;            // 0..511 slot index
      int R = s >> 3, sp = s & 7;
      int l = sp ^ (R & 7);             // logical slot (inverse swizzle)
      int grow = 2 * R + (l >> 2);      // logical row 0..127
      int gk = kt * 32 + (l & 3) * 8;
      int wub = (h * 256 + wid * 64) * 16;  // wave-uniform LDS base
      async_copy16(&ldsbuf[c][0] + wub, zb + (size_t)(i0 + grow) * H_N + gk);
      async_copy16(&ldsbuf[c][8192] + wub, tb + (size_t)(n0 + grow) * H_N + gk);
    }
  };

  // fragment byte offset for logical row r, k-block lhi (swizzled pair-packed)
  auto fragOff = [&](int r) {
    int R = r >> 1;
    int slot = (r & 1) * 4 + lhi;
    return R * 128 + ((slot ^ (R & 7)) * 16);
  };

  stage(0, 0);
  asm volatile("s_waitcnt vmcnt(0)" ::: "memory");
  __builtin_amdgcn_s_barrier();

  for (int t = 0; t < NT_K; ++t) {
    if (t + 1 < NT_K) stage((t + 1) & 1, t + 1);  // issue early, wait late
    const char* A = &ldsbuf[t & 1][0];
    const char* B = &ldsbuf[t & 1][8192];
    short8 a[4], b[4];
#pragma unroll
    for (int m = 0; m < 4; ++m) a[m] = *(const short8*)(A + fragOff(wr * 64 + m * 16 + llo));
#pragma unroll
    for (int n = 0; n < 4; ++n) b[n] = *(const short8*)(B + fragOff(wc * 64 + n * 16 + llo));
    asm volatile("s_waitcnt lgkmcnt(0)" ::: "memory");
    __builtin_amdgcn_sched_barrier(0);  // rule #18
    __builtin_amdgcn_s_setprio(1);
#pragma unroll
    for (int m = 0; m < 4; ++m)
#pragma unroll
      for (int n = 0; n < 4; ++n)
        acc[m][n] =
            __builtin_amdgcn_mfma_f32_16x16x32_bf16(a[m], b[n], acc[m][n], 0, 0, 0);
    __builtin_amdgcn_s_setprio(0);
    asm volatile("s_waitcnt vmcnt(0)" ::: "memory");  // t+1 loads: ~tile in flight
    __builtin_amdgcn_s_barrier();  // publish buf[(t+1)&1]
  }
  __syncthreads();  // fence before overlaying epilogue arrays onto ldsbuf

  // ---- fused epilogue: exp + masks + row/col reductions (LDS overlay) ----
  float* rpos = (float*)&ldsbuf[0][0];
  float* rneg = rpos + 128;
  float* cpos = rneg + 128;
  float* cneg = cpos + 128;
  float* rnorm = cneg + 128;
  float* cnorm = rnorm + 128;
  int* rowlab = (int*)(cnorm + 128);
  int* colj = rowlab + 128;
  int* coll = colj + 128;
  int* collab = coll + 128;

  if (tid < 128) {
    rowlab[tid] = labels[i0 + tid];
    rnorm[tid] = zn_inv[i0 + tid] * TEMP_INV;
    int c = n0 + tid;
    int j = c / 5;
    colj[tid] = j;
    coll[tid] = c - j * 5;
    collab[tid] = labels[j];
    cnorm[tid] = thn_inv[c];
    rpos[tid] = 0.f; rneg[tid] = 0.f; cpos[tid] = 0.f; cneg[tid] = 0.f;
  }
  __syncthreads();

  int cl[4], jg[4], lv[4], lj[4];
  float cs[4];
#pragma unroll
  for (int ni = 0; ni < 4; ++ni) {
    cl[ni] = wc * 64 + ni * 16 + llo;
    jg[ni] = colj[cl[ni]];
    lv[ni] = coll[cl[ni]];
    lj[ni] = collab[cl[ni]];
    cs[ni] = cnorm[cl[ni]];
  }
  float cpAcc[4] = {}, cnAcc[4] = {};
#pragma unroll
  for (int mi = 0; mi < 4; ++mi) {
#pragma unroll
    for (int r = 0; r < 4; ++r) {
      int rl = wr * 64 + mi * 16 + lhi * 4 + r;
      int ig = i0 + rl;
      int li = rowlab[rl];
      float rscale = rnorm[rl];
      float rp = 0.f, rn = 0.f;
#pragma unroll
      for (int ni = 0; ni < 4; ++ni) {
        float e = __expf(acc[mi][ni][r] * rscale * cs[ni]);
        bool same = (li == lj[ni]);
        bool diag = (ig == jg[ni]);
        if (same) {
          if (!diag && lv[ni] == li) { rp += e; cpAcc[ni] += e; }
        } else {
          rn += e;
          if (lv[ni] == lj[ni]) cnAcc[ni] += e;
        }
      }
      if (rp != 0.f) atomicAdd(&rpos[rl], rp);
      if (rn != 0.f) atomicAdd(&rneg[rl], rn);
    }
  }
#pragma unroll
  for (int ni = 0; ni < 4; ++ni) {
    if (cpAcc[ni] != 0.f) atomicAdd(&cpos[cl[ni]], cpAcc[ni]);
    if (cnAcc[ni] != 0.f) atomicAdd(&cneg[cl[ni]], cnAcc[ni]);
  }
  __syncthreads();
  if (tid < 128) {
    float v;
    v = rpos[tid]; if (v != 0.f) atomicAdd(&pos_z[i0 + tid], v);
    v = rneg[tid]; if (v != 0.f) atomicAdd(&neg_z[i0 + tid], v);
    int j = colj[tid];
    v = cpos[tid]; if (v != 0.f) atomicAdd(&pos_t[j], v);
    v = cneg[tid]; if (v != 0.f) atomicAdd(&neg_t[j], v);
  }
}

// ---------- K8: final loss ----------
__global__ __launch_bounds__(256) void loss_kernel(
    const float* __restrict__ pos_z, const float* __restrict__ neg_z,
    const float* __restrict__ pos_t, const float* __restrict__ neg_t,
    const int* __restrict__ labels, const int* __restrict__ cnt,
    float* __restrict__ out_loss) {
  __shared__ float sbuf[4];
  int i = blockIdx.x * 256 + threadIdx.x;
  float term = 0.f;
  int li = labels[i];
  if (cnt[li] > 1) {
    float pz = pos_z[i], nz = neg_z[i];
    float pt = pos_t[i], nt = neg_t[i];
    term = -logf(pz / (pz + nz + 1e-8f)) - logf(pt / (pt + nt + 1e-8f));
  }
  float s = block_reduce_sum256(term, sbuf);
  if (threadIdx.x == 0) atomicAdd(out_loss, s * (1.0f / B_N));
}

// ---------- launch ----------
extern "C" void kernel_launch(void* const* d_in, const int* in_sizes, int n_in,
                              void* d_out, int out_size, void* d_ws, size_t ws_size,
                              hipStream_t stream) {
  const float* seq = (const float*)d_in[0];
  const float* cls_gamma = (const float*)d_in[1];
  const float* cls_beta = (const float*)d_in[2];
  const float* cls_W = (const float*)d_in[3];
  const float* cls_b = (const float*)d_in[4];
  const float* label_gamma = (const float*)d_in[5];
  const float* label_beta = (const float*)d_in[6];
  const float* label_W = (const float*)d_in[7];
  const float* label_b = (const float*)d_in[8];
  const int* labels = (const int*)d_in[9];
  float* out = (float*)d_out;
  float* ws = (float*)d_ws;

  constexpr size_t OFF_SUMZ = 0;
  constexpr size_t OFF_SSQZ = 768;
  constexpr size_t OFF_SUMT = 1536;
  constexpr size_t OFF_SSQT = 2304;
  constexpr size_t OFF_POSZ = 3072;
  constexpr size_t OFF_NEGZ = 7168;
  constexpr size_t OFF_POST = 11264;
  constexpr size_t OFF_NEGT = 15360;
  constexpr size_t OFF_CNT = 19456;  // 8 ints
  constexpr size_t ZERO_FLOATS = 19464;
  constexpr size_t OFF_SZS = 19464;
  constexpr size_t OFF_SZT = 20232;
  constexpr size_t OFF_STS = 21000;
  constexpr size_t OFF_STT = 21768;
  constexpr size_t OFF_ZNI = 22536;     // 4096
  constexpr size_t OFF_TNI = 26632;     // 20480
  constexpr size_t OFF_CPRIME = 47112;  // 768
  constexpr size_t OFF_ZP = 47880;      // 4096*768 fp32
  constexpr size_t OFF_U = OFF_ZP + (size_t)B_N * H_N;
  constexpr size_t F32_END = OFF_U + (size_t)B_N * H_N;
  constexpr size_t BYTE_ZB = F32_END * sizeof(float);
  constexpr size_t BYTE_TB = BYTE_ZB + (size_t)B_N * H_N * 2;
  constexpr size_t BYTE_ZPB = BYTE_TB + (size_t)B_N * L_N * H_N * 2;
  constexpr size_t BYTE_WCB = BYTE_ZPB + (size_t)B_N * H_N * 2;
  constexpr size_t BYTE_WLT = BYTE_WCB + (size_t)H_N * H_N * 2;
  constexpr size_t TOTAL_BYTES = BYTE_WLT + (size_t)H_N * H_N * 2;
  if (ws_size < TOTAL_BYTES) return;

  __hip_bfloat16* zb = (__hip_bfloat16*)((char*)d_ws + BYTE_ZB);
  __hip_bfloat16* tb = (__hip_bfloat16*)((char*)d_ws + BYTE_TB);
  __hip_bfloat16* zpb = (__hip_bfloat16*)((char*)d_ws + BYTE_ZPB);
  __hip_bfloat16* wcb = (__hip_bfloat16*)((char*)d_ws + BYTE_WCB);
  __hip_bfloat16* wlt = (__hip_bfloat16*)((char*)d_ws + BYTE_WLT);

  hipMemsetAsync(d_ws, 0, ZERO_FLOATS * sizeof(float), stream);
  hipMemsetAsync((char*)d_out + (size_t)B_N * L_N * sizeof(float), 0, sizeof(float),
                 stream);

  extract_kernel<<<512, 256, 0, stream>>>(seq, zb, tb, ws + OFF_ZNI, ws + OFF_TNI,
                                          ws + OFF_SUMZ, ws + OFF_SSQZ,
                                          ws + OFF_SUMT, ws + OFF_SSQT);
  count_kernel<<<16, 256, 0, stream>>>(labels, (int*)(ws + OFF_CNT));
  finalize_kernel<<<3, 256, 0, stream>>>(
      ws + OFF_SUMZ, ws + OFF_SSQZ, ws + OFF_SUMT, ws + OFF_SSQT, cls_gamma,
      cls_beta, label_gamma, label_beta, ws + OFF_SZS, ws + OFF_SZT, ws + OFF_STS,
      ws + OFF_STT);
  prep_cls_kernel<<<H_N, 256, 0, stream>>>(cls_W, ws + OFF_SZS, ws + OFF_SZT, cls_b,
                                           wcb, ws + OFF_CPRIME);
  transpose_wl_kernel<<<dim3(24, 24), 256, 0, stream>>>(label_W, wlt);
  gemm128_kernel<true, true><<<dim3(32, 6), 256, 0, stream>>>(
      zb, wcb, ws + OFF_CPRIME, ws + OFF_ZP, zpb);
  gemm128_kernel<false, false><<<dim3(32, 6), 256, 0, stream>>>(
      zpb, wlt, nullptr, ws + OFF_U, nullptr);
  logits_kernel<<<B_N, 256, 0, stream>>>(seq, ws + OFF_U, ws + OFF_ZP, ws + OFF_STS,
                                         ws + OFF_STT, label_b, out);
  sgemm_fused_kernel<<<5120, 256, 0, stream>>>(
      zb, tb, ws + OFF_ZNI, ws + OFF_TNI, labels, ws + OFF_POSZ, ws + OFF_NEGZ,
      ws + OFF_POST, ws + OFF_NEGT);
  loss_kernel<<<16, 256, 0, stream>>>(ws + OFF_POSZ, ws + OFF_NEGZ, ws + OFF_POST,
                                      ws + OFF_NEGT, labels,
                                      (const int*)(ws + OFF_CNT),
                                      out + (size_t)B_N * L_N);
}